// Round 6
// baseline (82.883 us; speedup 1.0000x reference)
//
#include <hip/hip_runtime.h>
#include <stdint.h>

// ContrastiveLoss: mean over all pairs of (same-label ? d2 : relu(1-dist)^2)
// z: [8192,128] fp32, labels: [8192] int32. Output: 1 fp32 scalar.
//
// R15: BARRIER-FREE streaming loss kernel. Cold-premium theories falsified:
// traffic (R13 null), dirty-handoff/fill-concurrency (R14 null). The 18us
// premium is cache-state-INSENSITIVE -> it lives in the staging machinery's
// ~2080 chip-wide serialization points (vmcnt(0)+2x syncthreads per tile,
// 70KB-LDS WG dispatch). zb (1MB) + sq/labels (64KB) are L2-resident, so
// LDS staging is unnecessary: the LDS copy was LINEAR (ldsX[off]==panel[off]
// byte-for-byte), so every ds_read becomes a global_load_dwordx2 at the
// SAME offset. All per-tile offsets are tile-invariant (hoisted by LICM);
// only 2 SGPR panel bases change per tile. Zero barriers, zero staging,
// zero LDS (except 32B reduce), no vmcnt(0) convoy. Cold misses overlap
// with compute via thousands of independent in-flight loads.
// Kept: fp8 MFMA core math, granule swizzle baked in zb, deferred
// wave-vote epilogue, XCD-local int-only tile decode (R13), single
// atomicAdd finish (R11). prep identical to verified R13.

#define NROWS 8192
#define DIMK  128
#define NB    64                     // 8192 / 128
#define NPERS 512                    // persistent blocks (2 per CU)

typedef __attribute__((ext_vector_type(4))) float f32x4;

// Convert z -> fp8 e4m3 with granule-swizzled rows: logical k lives in
// granule g = ((k>>3)&3)<<2 | (k>>5), stored at byte ((g^(row&15))<<3)+(k&7).
// Dot-invariant. Also per-row sum of squares of ROUNDED values (diag d2==0).
__global__ __launch_bounds__(256) void prep_kernel(
    const float* __restrict__ z, unsigned char* __restrict__ zb,
    float* __restrict__ sq) {
  int tid = threadIdx.x;
  int row = (blockIdx.x << 3) + (tid >> 5);          // 8 rows per block
  int c32 = tid & 31;                                // 32 lanes per row
  float4 x = ((const float4*)(z + (size_t)row * DIMK))[c32];
  int u = __builtin_amdgcn_cvt_pk_fp8_f32(x.x, x.y, 0, false);
  u     = __builtin_amdgcn_cvt_pk_fp8_f32(x.z, x.w, u, true);
  float r0 = __builtin_amdgcn_cvt_f32_fp8(u, 0);
  float r1 = __builtin_amdgcn_cvt_f32_fp8(u, 1);
  float r2 = __builtin_amdgcn_cvt_f32_fp8(u, 2);
  float r3 = __builtin_amdgcn_cvt_f32_fp8(u, 3);
  float s = (r0 * r0 + r1 * r1) + (r2 * r2 + r3 * r3);
  int k0 = c32 << 2;                                 // logical k of byte 0
  int g  = (((k0 >> 3) & 3) << 2) | (k0 >> 5);       // granule index
  int p  = ((g ^ (row & 15)) << 3) + (k0 & 7);       // 4B-aligned
  *(uint32_t*)(zb + (size_t)row * DIMK + p) = (uint32_t)u;
  #pragma unroll
  for (int off = 16; off; off >>= 1) s += __shfl_down(s, off, 32);
  if (c32 == 0) sq[row] = s;
}

// XCD-local decode: XCD x owns rows r = x, x+8, ..., x+56. Row r has
// (NB - r) tiles. Flattened index n within the owned set -> (bi, bj).
// Integer-only, uniform (blockIdx-derived) -> compiles to SALU.
__device__ __forceinline__ void decode_tile_x(int x, int n, int& bi, int& bj) {
  int rem = n, k = 0, len = NB - x;       // L_k = NB - x - 8k
  while (rem >= len) { rem -= len; ++k; len -= 8; }
  bi = x + (k << 3);
  bj = bi + rem;
}

// Persistent: 512 blocks x 512 thr (8 waves, 4x2). Block b = (x = b&7,
// slot s = b>>3) computes its XCD's tiles n = s, s+64, ... (< 288-8x).
// Pure streaming: MFMA A/B fragments and sq/labels read DIRECTLY from
// global (L2-resident) at the exact offsets the LDS copy used to hold.
// No barriers in the tile loop. Ends with ONE device-scope atomicAdd.
__global__ __launch_bounds__(512, 4) void loss_kernel(
    const unsigned char* __restrict__ zb, const float* __restrict__ sq,
    const int* __restrict__ labels, float* __restrict__ out) {
  __shared__ float red[8];

  int tid = threadIdx.x, lane = tid & 63, wave = tid >> 6;
  int wm = wave >> 1, wn = wave & 1;
  int lc = lane & 15;                                // frag row (A)/col (out)
  int q  = lane >> 4;                                // quad: k-granule select

  float psum_acc = 0.f;

  int x = blockIdx.x & 7;                            // XCD (round-robin)
  int s = blockIdx.x >> 3;                           // slot within XCD
  int tcount = 288 - 8 * x;                          // tiles owned by XCD x

  // Tile-invariant byte offsets (LICM hoists these out of the tile loop).
  int rA0 = ((wm << 5)      + lc) * 128;
  int rA1 = ((wm << 5) + 16 + lc) * 128;
  int rB0 = ((wn << 6)      + lc) * 128;
  int rB1 = ((wn << 6) + 16 + lc) * 128;
  int rB2 = ((wn << 6) + 32 + lc) * 128;
  int rB3 = ((wn << 6) + 48 + lc) * 128;

  for (int n = s; n < tcount; n += 64) {
    int bi, bj;
    decode_tile_x(x, n, bi, bj);
    const unsigned char* Ab = zb + (((size_t)bi << 7) * DIMK);
    const unsigned char* Bb = zb + (((size_t)bj << 7) * DIMK);

    f32x4 acc[2][4] = {};
    #pragma unroll
    for (int ks = 0; ks < 4; ++ks) {
      int so = ((((q << 2) | ks) ^ lc) << 3);        // swizzled slot offset
      long a0 = *(const long*)(Ab + rA0 + so);
      long a1 = *(const long*)(Ab + rA1 + so);
      long b0 = *(const long*)(Bb + rB0 + so);
      long b1 = *(const long*)(Bb + rB1 + so);
      long b2 = *(const long*)(Bb + rB2 + so);
      long b3 = *(const long*)(Bb + rB3 + so);
      acc[0][0] = __builtin_amdgcn_mfma_f32_16x16x32_fp8_fp8(a0, b0, acc[0][0], 0, 0, 0);
      acc[0][1] = __builtin_amdgcn_mfma_f32_16x16x32_fp8_fp8(a0, b1, acc[0][1], 0, 0, 0);
      acc[0][2] = __builtin_amdgcn_mfma_f32_16x16x32_fp8_fp8(a0, b2, acc[0][2], 0, 0, 0);
      acc[0][3] = __builtin_amdgcn_mfma_f32_16x16x32_fp8_fp8(a0, b3, acc[0][3], 0, 0, 0);
      acc[1][0] = __builtin_amdgcn_mfma_f32_16x16x32_fp8_fp8(a1, b0, acc[1][0], 0, 0, 0);
      acc[1][1] = __builtin_amdgcn_mfma_f32_16x16x32_fp8_fp8(a1, b1, acc[1][1], 0, 0, 0);
      acc[1][2] = __builtin_amdgcn_mfma_f32_16x16x32_fp8_fp8(a1, b2, acc[1][2], 0, 0, 0);
      acc[1][3] = __builtin_amdgcn_mfma_f32_16x16x32_fp8_fp8(a1, b3, acc[1][3], 0, 0, 0);
    }

    // ---- epilogue: branchless fast pass + ONE deferred vote ----
    // sq/labels read directly (L2-hot); offsets tile-invariant, bases per-tile.
    const float* sqA = sq     + ((size_t)bi << 7);
    const int*   laA = labels + ((size_t)bi << 7);
    const float* sqB = sq     + ((size_t)bj << 7);
    const int*   laB = labels + ((size_t)bj << 7);

    int r0 = q << 2;
    float sn_[4]; int ln_[4];
    #pragma unroll
    for (int j = 0; j < 4; ++j) {
      int nidx = (wn << 6) + (j << 4) + lc;
      sn_[j] = sqB[nidx]; ln_[j] = laB[nidx];
    }
    float ps0 = 0.f, ps1 = 0.f, ps2 = 0.f, ps3 = 0.f;
    float mnall = 1e30f;
    #pragma unroll
    for (int i = 0; i < 2; ++i) {
      int mb = (wm << 5) + (i << 4) + r0;
      f32x4 sm4 = *(const f32x4*)&sqA[mb];
      int4  lm4 = *(const int4*)&laA[mb];
      #pragma unroll
      for (int j = 0; j < 4; ++j) {
        float d0  = fmaf(-2.f, acc[i][j][0], sm4[0] + sn_[j]);
        float d1  = fmaf(-2.f, acc[i][j][1], sm4[1] + sn_[j]);
        float d2_ = fmaf(-2.f, acc[i][j][2], sm4[2] + sn_[j]);
        float d3  = fmaf(-2.f, acc[i][j][3], sm4[3] + sn_[j]);
        mnall = fminf(mnall, fminf(fminf(d0, d1), fminf(d2_, d3)));
        ps0 += (lm4.x == ln_[j]) ? d0  : 0.f;
        ps1 += (lm4.y == ln_[j]) ? d1  : 0.f;
        ps2 += (lm4.z == ln_[j]) ? d2_ : 0.f;
        ps3 += (lm4.w == ln_[j]) ? d3  : 0.f;
      }
    }
    if (__builtin_expect(__any(mnall < 1.f), 0)) {
      // exact slow path (diagonal-touching waves only); acc still live
      ps0 = ps1 = ps2 = ps3 = 0.f;
      #pragma unroll
      for (int i = 0; i < 2; ++i) {
        int mb = (wm << 5) + (i << 4) + r0;
        f32x4 sm4 = *(const f32x4*)&sqA[mb];
        int4  lm4 = *(const int4*)&laA[mb];
        #pragma unroll
        for (int j = 0; j < 4; ++j) {
          float dc, tt;
          dc = fmaxf(fmaf(-2.f, acc[i][j][0], sm4[0] + sn_[j]), 0.f);
          tt = fmaxf(1.f - sqrtf(dc), 0.f);
          ps0 += (lm4.x == ln_[j]) ? dc : tt * tt;
          dc = fmaxf(fmaf(-2.f, acc[i][j][1], sm4[1] + sn_[j]), 0.f);
          tt = fmaxf(1.f - sqrtf(dc), 0.f);
          ps1 += (lm4.y == ln_[j]) ? dc : tt * tt;
          dc = fmaxf(fmaf(-2.f, acc[i][j][2], sm4[2] + sn_[j]), 0.f);
          tt = fmaxf(1.f - sqrtf(dc), 0.f);
          ps2 += (lm4.z == ln_[j]) ? dc : tt * tt;
          dc = fmaxf(fmaf(-2.f, acc[i][j][3], sm4[3] + sn_[j]), 0.f);
          tt = fmaxf(1.f - sqrtf(dc), 0.f);
          ps3 += (lm4.w == ln_[j]) ? dc : tt * tt;
        }
      }
    }
    float w = (bi == bj) ? 1.f : 2.f;                // symmetry weight
    psum_acc += w * ((ps0 + ps1) + (ps2 + ps3));
  }

  // ---- block reduction + ONE device-scope atomicAdd ----
  psum_acc *= (1.f / (8192.f * 8192.f));             // 2^-26, exact
  #pragma unroll
  for (int off = 32; off; off >>= 1) psum_acc += __shfl_down(psum_acc, off);
  if (lane == 0) red[wave] = psum_acc;
  __syncthreads();
  if (tid == 0) {
    float sum = 0.f;
    #pragma unroll
    for (int k = 0; k < 8; ++k) sum += red[k];
    atomicAdd(out, sum);                             // device-scope default
  }
}

extern "C" void kernel_launch(void* const* d_in, const int* in_sizes, int n_in,
                              void* d_out, int out_size, void* d_ws, size_t ws_size,
                              hipStream_t stream) {
  const float* z      = (const float*)d_in[0];
  const int*   labels = (const int*)d_in[1];
  float*       out    = (float*)d_out;
  unsigned char* zb   = (unsigned char*)d_ws;                         // 1 MB
  float* sq           = (float*)((char*)d_ws + (size_t)NROWS * DIMK); // 32 KB

  prep_kernel<<<NROWS / 8, 256, 0, stream>>>(z, zb, sq);
  loss_kernel<<<NPERS, 512, 0, stream>>>(zb, sq, labels, out);
}

// Round 7
// 72.967 us; speedup vs baseline: 1.1359x; 1.1359x over previous
//
#include <hip/hip_runtime.h>
#include <stdint.h>

// ContrastiveLoss: mean over all pairs of (same-label ? d2 : relu(1-dist)^2)
// z: [8192,128] fp32, labels: [8192] int32. Output: 1 fp32 scalar.
//
// R16: R13 structure (best, 72.9us) + ONE change: prep stores zb/sq at
// DEVICE SCOPE (sc0 sc1 write-through). Premium ledger: traffic volume
// (R13 null), fill-concurrency warmup + nt-hint (R14 null), barrier
// convoys (R15 WORSE). Surviving theory: prep's plain stores leave zb
// dirty in the writing XCD's L2 (rows scattered round-robin); each XCD's
// first read of each line (~8MB of cross-XCD dirty probes, invisible in
// FETCH_SIZE) is latency/concurrency-bound => ~18us premium. R14's nt was
// only an LRU hint (still allocates dirty locally) -> why its warmup
// couldn't help. Device-scope stores must be visible past the local L2
// => write through to L3; loss's first reads become clean concurrent L3
// fills. Predicted: loss cold 29.4 -> ~13-17us, end-to-end ~58-63us.
// Everything else byte-identical to verified R13.

#define NROWS 8192
#define DIMK  128
#define NB    64                     // 8192 / 128
#define NPERS 512                    // persistent blocks (2 per CU)

typedef __attribute__((ext_vector_type(4))) float f32x4;

#define AS_GLOBAL __attribute__((address_space(1)))
#define AS_LDS    __attribute__((address_space(3)))

// Convert z -> fp8 e4m3 with granule-swizzled rows: logical k lives in
// granule g = ((k>>3)&3)<<2 | (k>>5), stored at byte ((g^(row&15))<<3)+(k&7).
// Dot-invariant. Also per-row sum of squares of ROUNDED values (diag d2==0).
// Stores are DEVICE-SCOPE (sc0 sc1): write through the local L2 so lines
// are NOT left dirty in the producing XCD -> no cross-XCD probe storm.
__global__ __launch_bounds__(256) void prep_kernel(
    const float* __restrict__ z, unsigned char* __restrict__ zb,
    float* __restrict__ sq) {
  int tid = threadIdx.x;
  int row = (blockIdx.x << 3) + (tid >> 5);          // 8 rows per block
  int c32 = tid & 31;                                // 32 lanes per row
  float4 x = ((const float4*)(z + (size_t)row * DIMK))[c32];
  int u = __builtin_amdgcn_cvt_pk_fp8_f32(x.x, x.y, 0, false);
  u     = __builtin_amdgcn_cvt_pk_fp8_f32(x.z, x.w, u, true);
  float r0 = __builtin_amdgcn_cvt_f32_fp8(u, 0);
  float r1 = __builtin_amdgcn_cvt_f32_fp8(u, 1);
  float r2 = __builtin_amdgcn_cvt_f32_fp8(u, 2);
  float r3 = __builtin_amdgcn_cvt_f32_fp8(u, 3);
  float s = (r0 * r0 + r1 * r1) + (r2 * r2 + r3 * r3);
  int k0 = c32 << 2;                                 // logical k of byte 0
  int g  = (((k0 >> 3) & 3) << 2) | (k0 >> 5);       // granule index
  int p  = ((g ^ (row & 15)) << 3) + (k0 & 7);       // 4B-aligned
  __hip_atomic_store((uint32_t*)(zb + (size_t)row * DIMK + p), (uint32_t)u,
                     __ATOMIC_RELAXED, __HIP_MEMORY_SCOPE_AGENT);
  #pragma unroll
  for (int off = 16; off; off >>= 1) s += __shfl_down(s, off, 32);
  if (c32 == 0)
    __hip_atomic_store(sq + row, s,
                       __ATOMIC_RELAXED, __HIP_MEMORY_SCOPE_AGENT);
}

// XCD-local decode: XCD x owns rows r = x, x+8, ..., x+56. Row r has
// (NB - r) tiles. Flattened index n within the owned set -> (bi, bj).
// Integer-only, uniform (blockIdx-derived) -> compiles to SALU.
__device__ __forceinline__ void decode_tile_x(int x, int n, int& bi, int& bj) {
  int rem = n, k = 0, len = NB - x;       // L_k = NB - x - 8k
  while (rem >= len) { rem -= len; ++k; len -= 8; }
  bi = x + (k << 3);
  bj = bi + rem;
}

// Persistent: 512 blocks x 512 thr (8 waves, 4x2). Block b = (x = b&7,
// slot s = b>>3) computes its XCD's tiles n = s, s+64, ... (< 288-8x),
// double-buffered staging. Ends with ONE device-scope atomicAdd.
__global__ __launch_bounds__(512, 4) void loss_kernel(
    const unsigned char* __restrict__ zb, const float* __restrict__ sq,
    const int* __restrict__ labels, float* __restrict__ out) {
  __shared__ __align__(16) unsigned char buf[2][32768];   // [A 16K | B 16K]
  __shared__ __align__(16) unsigned char sqlab[2][2048];  // [sqA|laA|sqB|laB]
  __shared__ float red[8];

  int tid = threadIdx.x, lane = tid & 63, wave = tid >> 6;
  int wm = wave >> 1, wn = wave & 1;
  int lc = lane & 15;                                // frag row (A)/col (out)
  int q  = lane >> 4;                                // quad: k-granule select

  // sq/label staging role for this wave (one masked DMA per tile):
  //   w0,w1->sqA halves; w2,w3->laA; w4,w5->sqB; w6,w7->laB
  int sl_isB  = wave >> 2;
  int sl_isLa = (wave >> 1) & 1;
  int sl_half = wave & 1;

  float psum_acc = 0.f;

  int x = blockIdx.x & 7;                            // XCD (round-robin)
  int s = blockIdx.x >> 3;                           // slot within XCD
  int tcount = 288 - 8 * x;                          // tiles owned by XCD x
  int n = s;

  int bi, bj;
  decode_tile_x(x, n, bi, bj);

  // ---- prologue: stage tile n into buffer 0 ----
  {
    const unsigned char* Ab = zb + (((size_t)bi << 7) * DIMK);
    const unsigned char* Bb = zb + (((size_t)bj << 7) * DIMK);
    #pragma unroll
    for (int it = 0; it < 2; ++it) {
      int L0 = (it << 9) + (wave << 6);
      __builtin_amdgcn_global_load_lds(
          (const AS_GLOBAL void*)(uintptr_t)(Ab + (size_t)(L0 + lane) * 16),
          (AS_LDS void*)(uintptr_t)(&buf[0][(size_t)L0 * 16]), 16, 0, 0);
      __builtin_amdgcn_global_load_lds(
          (const AS_GLOBAL void*)(uintptr_t)(Bb + (size_t)(L0 + lane) * 16),
          (AS_LDS void*)(uintptr_t)(&buf[0][16384 + (size_t)L0 * 16]), 16, 0, 0);
    }
    const char* p0 = sl_isLa ? (const char*)labels : (const char*)sq;
    const char* src = p0 + ((size_t)((sl_isB ? bj : bi) << 7) << 2)
                         + (sl_half << 8);
    if (lane < 16)
      __builtin_amdgcn_global_load_lds(
          (const AS_GLOBAL void*)(uintptr_t)(src + lane * 16),
          (AS_LDS void*)(uintptr_t)(&sqlab[0][wave << 8]), 16, 0, 0);
  }

  int cur = 0;
  for (;; n += 64) {
    int nn = n + 64;
    bool hasNext = nn < tcount;

    // ---- wait for current tile's DMA (issued a full iteration ago) ----
    asm volatile("s_waitcnt vmcnt(0)" ::: "memory");
    __syncthreads();   // implicit drain is free: vmcnt already 0

    // ---- prefetch next tile into the other buffer ----
    int bin = bi, bjn = bj;
    if (hasNext) {
      decode_tile_x(x, nn, bin, bjn);
      int nc = cur ^ 1;
      const unsigned char* Ab = zb + (((size_t)bin << 7) * DIMK);
      const unsigned char* Bb = zb + (((size_t)bjn << 7) * DIMK);
      #pragma unroll
      for (int it = 0; it < 2; ++it) {
        int L0 = (it << 9) + (wave << 6);
        __builtin_amdgcn_global_load_lds(
            (const AS_GLOBAL void*)(uintptr_t)(Ab + (size_t)(L0 + lane) * 16),
            (AS_LDS void*)(uintptr_t)(&buf[nc][(size_t)L0 * 16]), 16, 0, 0);
        __builtin_amdgcn_global_load_lds(
            (const AS_GLOBAL void*)(uintptr_t)(Bb + (size_t)(L0 + lane) * 16),
            (AS_LDS void*)(uintptr_t)(&buf[nc][16384 + (size_t)L0 * 16]), 16, 0, 0);
      }
      const char* p0 = sl_isLa ? (const char*)labels : (const char*)sq;
      const char* src = p0 + ((size_t)((sl_isB ? bjn : bin) << 7) << 2)
                           + (sl_half << 8);
      if (lane < 16)
        __builtin_amdgcn_global_load_lds(
            (const AS_GLOBAL void*)(uintptr_t)(src + lane * 16),
            (AS_LDS void*)(uintptr_t)(&sqlab[nc][wave << 8]), 16, 0, 0);
    }

    // ---- compute tile n from buf[cur] ----
    const unsigned char* ldsA = &buf[cur][0];
    const unsigned char* ldsB = &buf[cur][16384];
    const float* sqAl = (const float*)&sqlab[cur][0];
    const int*   laAl = (const int*)&sqlab[cur][512];
    const float* sqBl = (const float*)&sqlab[cur][1024];
    const int*   laBl = (const int*)&sqlab[cur][1536];

    f32x4 acc[2][4] = {};
    #pragma unroll
    for (int ks = 0; ks < 4; ++ks) {
      int so = ((((q << 2) | ks) ^ lc) << 3);        // swizzled slot offset
      long a0 = *(const long*)(ldsA + ((wm << 5)      + lc) * 128 + so);
      long a1 = *(const long*)(ldsA + ((wm << 5) + 16 + lc) * 128 + so);
      long b0 = *(const long*)(ldsB + ((wn << 6)      + lc) * 128 + so);
      long b1 = *(const long*)(ldsB + ((wn << 6) + 16 + lc) * 128 + so);
      long b2 = *(const long*)(ldsB + ((wn << 6) + 32 + lc) * 128 + so);
      long b3 = *(const long*)(ldsB + ((wn << 6) + 48 + lc) * 128 + so);
      acc[0][0] = __builtin_amdgcn_mfma_f32_16x16x32_fp8_fp8(a0, b0, acc[0][0], 0, 0, 0);
      acc[0][1] = __builtin_amdgcn_mfma_f32_16x16x32_fp8_fp8(a0, b1, acc[0][1], 0, 0, 0);
      acc[0][2] = __builtin_amdgcn_mfma_f32_16x16x32_fp8_fp8(a0, b2, acc[0][2], 0, 0, 0);
      acc[0][3] = __builtin_amdgcn_mfma_f32_16x16x32_fp8_fp8(a0, b3, acc[0][3], 0, 0, 0);
      acc[1][0] = __builtin_amdgcn_mfma_f32_16x16x32_fp8_fp8(a1, b0, acc[1][0], 0, 0, 0);
      acc[1][1] = __builtin_amdgcn_mfma_f32_16x16x32_fp8_fp8(a1, b1, acc[1][1], 0, 0, 0);
      acc[1][2] = __builtin_amdgcn_mfma_f32_16x16x32_fp8_fp8(a1, b2, acc[1][2], 0, 0, 0);
      acc[1][3] = __builtin_amdgcn_mfma_f32_16x16x32_fp8_fp8(a1, b3, acc[1][3], 0, 0, 0);
    }

    // ---- epilogue: branchless fast pass + ONE deferred vote ----
    // C/D layout: col = lane&15, row = (lane>>4)*4 + reg. If every d2 in
    // this wave's outputs >= 1: non-eq term EXACTLY 0, eq term exactly d2.
    int r0 = q << 2;
    float sn_[4]; int ln_[4];
    #pragma unroll
    for (int j = 0; j < 4; ++j) {
      int nidx = (wn << 6) + (j << 4) + lc;
      sn_[j] = sqBl[nidx]; ln_[j] = laBl[nidx];
    }
    float ps0 = 0.f, ps1 = 0.f, ps2 = 0.f, ps3 = 0.f;
    float mnall = 1e30f;
    #pragma unroll
    for (int i = 0; i < 2; ++i) {
      int mb = (wm << 5) + (i << 4) + r0;
      f32x4 sm4 = *(const f32x4*)&sqAl[mb];
      int4  lm4 = *(const int4*)&laAl[mb];
      #pragma unroll
      for (int j = 0; j < 4; ++j) {
        float d0  = fmaf(-2.f, acc[i][j][0], sm4[0] + sn_[j]);
        float d1  = fmaf(-2.f, acc[i][j][1], sm4[1] + sn_[j]);
        float d2_ = fmaf(-2.f, acc[i][j][2], sm4[2] + sn_[j]);
        float d3  = fmaf(-2.f, acc[i][j][3], sm4[3] + sn_[j]);
        mnall = fminf(mnall, fminf(fminf(d0, d1), fminf(d2_, d3)));
        ps0 += (lm4.x == ln_[j]) ? d0  : 0.f;
        ps1 += (lm4.y == ln_[j]) ? d1  : 0.f;
        ps2 += (lm4.z == ln_[j]) ? d2_ : 0.f;
        ps3 += (lm4.w == ln_[j]) ? d3  : 0.f;
      }
    }
    if (__builtin_expect(__any(mnall < 1.f), 0)) {
      // exact slow path (diagonal-touching waves only); acc still live
      ps0 = ps1 = ps2 = ps3 = 0.f;
      #pragma unroll
      for (int i = 0; i < 2; ++i) {
        int mb = (wm << 5) + (i << 4) + r0;
        f32x4 sm4 = *(const f32x4*)&sqAl[mb];
        int4  lm4 = *(const int4*)&laAl[mb];
        #pragma unroll
        for (int j = 0; j < 4; ++j) {
          float dc, tt;
          dc = fmaxf(fmaf(-2.f, acc[i][j][0], sm4[0] + sn_[j]), 0.f);
          tt = fmaxf(1.f - sqrtf(dc), 0.f);
          ps0 += (lm4.x == ln_[j]) ? dc : tt * tt;
          dc = fmaxf(fmaf(-2.f, acc[i][j][1], sm4[1] + sn_[j]), 0.f);
          tt = fmaxf(1.f - sqrtf(dc), 0.f);
          ps1 += (lm4.y == ln_[j]) ? dc : tt * tt;
          dc = fmaxf(fmaf(-2.f, acc[i][j][2], sm4[2] + sn_[j]), 0.f);
          tt = fmaxf(1.f - sqrtf(dc), 0.f);
          ps2 += (lm4.z == ln_[j]) ? dc : tt * tt;
          dc = fmaxf(fmaf(-2.f, acc[i][j][3], sm4[3] + sn_[j]), 0.f);
          tt = fmaxf(1.f - sqrtf(dc), 0.f);
          ps3 += (lm4.w == ln_[j]) ? dc : tt * tt;
        }
      }
    }
    float w = (bi == bj) ? 1.f : 2.f;                // symmetry weight
    psum_acc += w * ((ps0 + ps1) + (ps2 + ps3));

    if (!hasNext) break;
    bi = bin; bj = bjn; cur ^= 1;
  }

  // ---- block reduction + ONE device-scope atomicAdd ----
  psum_acc *= (1.f / (8192.f * 8192.f));             // 2^-26, exact
  #pragma unroll
  for (int off = 32; off; off >>= 1) psum_acc += __shfl_down(psum_acc, off);
  if (lane == 0) red[wave] = psum_acc;
  __syncthreads();
  if (tid == 0) {
    float sum = 0.f;
    #pragma unroll
    for (int k = 0; k < 8; ++k) sum += red[k];
    atomicAdd(out, sum);                             // device-scope default
  }
}

extern "C" void kernel_launch(void* const* d_in, const int* in_sizes, int n_in,
                              void* d_out, int out_size, void* d_ws, size_t ws_size,
                              hipStream_t stream) {
  const float* z      = (const float*)d_in[0];
  const int*   labels = (const int*)d_in[1];
  float*       out    = (float*)d_out;
  unsigned char* zb   = (unsigned char*)d_ws;                         // 1 MB
  float* sq           = (float*)((char*)d_ws + (size_t)NROWS * DIMK); // 32 KB

  prep_kernel<<<NROWS / 8, 256, 0, stream>>>(z, zb, sq);
  loss_kernel<<<NPERS, 512, 0, stream>>>(zb, sq, labels, out);
}